// Round 18
// baseline (7868.944 us; speedup 1.0000x reference)
//
#include <hip/hip_runtime.h>

// BiLSTM-CRF forward on MI355X.
//   bias:    bias sums.
//   wtrans:  LDS-tiled transpose of W_ih to [k][row].
//   wquant:  per-row int8 quantization of W_hh (quad-quarter layout).
//   gin:     embedding gather + input projection -> gin[t][rp] (rp=u*4+gate).
//   lstm:    2 blocks x 1024 threads (16 waves). R18: reduce PEAK register
//            pressure below the 128-VGPR budget so the allocator stops
//            AGPR-homing w[64] (R15-R17 pin attempts all failed; peak was
//            ~135-140 regs with 16 live h dwords). h is now read in TWO
//            half-passes (2 x ds_read_b128 + 32 sdot each) separated by
//            sched_barrier(0) (stops load hoisting -> live h regs 16->8);
//            gin prefetch depth 2->1. Raw v_exp/v_rcp acts, LDS-only
//            barrier, incremental pointers (proven R13/R15/R16).
//   feats:   [hf,hr] @ w_out^T + b_out.
//   viterbi: max-plus chunk scan (vp_chunks/vp_scan/vp_replay, R14 proven)
//            + 3-phase parallel backtrace.

#define SEQ  8192
#define EMBD 256
#define HD   256
#define G4   1024
#define NEGV -10000.0f
#define NCH  256          // chunks
#define CLEN 32           // steps per chunk

#if __has_builtin(__builtin_amdgcn_sdot4)
__device__ __forceinline__ int SDOT4(unsigned a, unsigned b, int c) {
    return __builtin_amdgcn_sdot4((int)a, (int)b, c, false);
}
#else
__device__ __forceinline__ int SDOT4(unsigned a, unsigned b, int c) {
#pragma unroll
    for (int i = 0; i < 4; ++i) {
        int ai = (int)(a << (24 - 8 * i)) >> 24;
        int bi = (int)(b << (24 - 8 * i)) >> 24;
        c += ai * bi;
    }
    return c;
}
#endif

// LDS-only barrier: ds ops drained (h visibility), global ops stay in flight.
__device__ __forceinline__ void lds_barrier() {
    asm volatile("s_waitcnt lgkmcnt(0)\n\ts_barrier" ::: "memory");
}

// DPP quad_perm (VALU pipe)
template <int CTRL>
__device__ __forceinline__ float dpp_bcast(float x) {
    return __int_as_float(
        __builtin_amdgcn_mov_dpp(__float_as_int(x), CTRL, 0xf, 0xf, true));
}
template <int CTRL>
__device__ __forceinline__ int idpp(int x) {
    return __builtin_amdgcn_mov_dpp(x, CTRL, 0xf, 0xf, true);
}

__device__ __forceinline__ float bperm(int addr, float v) {
    return __int_as_float(__builtin_amdgcn_ds_bpermute(addr, __float_as_int(v)));
}

// raw transcendentals: v_exp_f32 computes 2^x; v_rcp_f32 ~1ulp reciprocal
__device__ __forceinline__ float fexp2(float x) {
    float r; asm("v_exp_f32 %0, %1" : "=v"(r) : "v"(x)); return r;
}
__device__ __forceinline__ float frcp(float x) {
    float r; asm("v_rcp_f32 %0, %1" : "=v"(r) : "v"(x)); return r;
}

// ---------------------------------------------------------------- bias sums
__global__ void bias_kernel(const float* __restrict__ b_ih_f, const float* __restrict__ b_hh_f,
                            const float* __restrict__ b_ih_r, const float* __restrict__ b_hh_r,
                            float* __restrict__ bs_f, float* __restrict__ bs_r) {
    int i = threadIdx.x;
#pragma unroll
    for (int m = 0; m < 4; ++m) {
        int row = i + 256 * m;
        bs_f[row] = b_ih_f[row] + b_hh_f[row];
        bs_r[row] = b_ih_r[row] + b_hh_r[row];
    }
}

// ---------------------------------------------------------------- W_ih transpose (tiled)
__global__ __launch_bounds__(256) void wtrans_kernel(
    const float* __restrict__ w_ih_f, const float* __restrict__ w_ih_r,
    float* __restrict__ wt_f, float* __restrict__ wt_r) {
    __shared__ float tile[32][257];
    int mat = blockIdx.x & 1;
    int r0  = (blockIdx.x >> 1) << 5;          // 0,32,...,992
    const float* src = mat ? w_ih_r : w_ih_f;
    float*       dst = mat ? wt_r   : wt_f;
    int tid = threadIdx.x;
    for (int r = 0; r < 32; ++r)
        tile[r][tid] = src[(size_t)(r0 + r) * EMBD + tid];
    __syncthreads();
    int row = tid & 31, kq = tid >> 5;
    for (int kb = 0; kb < EMBD; kb += 8) {
        int k = kb + kq;
        dst[(size_t)k * G4 + r0 + row] = tile[row][k];
    }
}

// ---------------------------------------------------------------- W_hh int8 quantization
// QUAD-QUARTER layout: wq[dir][(r*16+j)*1024 + u*4+g] = pack(W[row][g*64+4j ..]).
__global__ __launch_bounds__(64) void wquant_kernel(
    const float* __restrict__ w_hh_f, const float* __restrict__ w_hh_r,
    unsigned* __restrict__ wq, float* __restrict__ fac)
{
    int b = blockIdx.x;
    int dir = b >> 10, rp = b & 1023;
    int u = rp >> 2, r = rp & 3;
    int row = r * 256 + u;
    int l = threadIdx.x;
    int j = l & 15, g = l >> 4;
    const float* Wr = (dir ? w_hh_r : w_hh_f) + (size_t)row * HD;
    float4 v = reinterpret_cast<const float4*>(Wr)[g * 16 + j];   // k = g*64+4j
    float m = fmaxf(fmaxf(fabsf(v.x), fabsf(v.y)), fmaxf(fabsf(v.z), fabsf(v.w)));
#pragma unroll
    for (int off = 1; off < 64; off <<= 1) m = fmaxf(m, __shfl_xor(m, off));
    m = fmaxf(m, 1e-20f);
    float inv = 127.f / m;
    int q0 = (int)rintf(v.x * inv), q1 = (int)rintf(v.y * inv);
    int q2 = (int)rintf(v.z * inv), q3 = (int)rintf(v.w * inv);
    unsigned pk = (unsigned)(q0 & 0xff) | ((unsigned)(q1 & 0xff) << 8) |
                  ((unsigned)(q2 & 0xff) << 16) | ((unsigned)(q3 & 0xff) << 24);
    wq[(size_t)dir * 65536 + (size_t)(r * 16 + j) * 1024 + u * 4 + g] = pk;
    if (l == 0) fac[dir * 1024 + rp] = m / (127.f * 127.f);   // dequant scale
}

// ---------------------------------------------------------------- input projection
__global__ __launch_bounds__(256) void gin_kernel(
    const int* __restrict__ sentence, const float* __restrict__ emb,
    const float* __restrict__ wt_f, const float* __restrict__ wt_r,
    const float* __restrict__ bs_f, const float* __restrict__ bs_r,
    float* __restrict__ gin_f, float* __restrict__ gin_r)
{
    __shared__ float x_lds[32][EMBD];
    __shared__ int   sid_lds[32];
    int t0  = blockIdx.x * 32;
    int tid = threadIdx.x;
    if (tid < 32) sid_lds[tid] = sentence[t0 + tid];
    __syncthreads();
    for (int i = 0; i < 32; ++i)
        x_lds[i][tid] = emb[(size_t)sid_lds[i] * EMBD + tid];
    __syncthreads();

    float bsv[8];
#pragma unroll
    for (int m = 0; m < 4; ++m) bsv[m]     = bs_f[tid + 256 * m];
#pragma unroll
    for (int m = 0; m < 4; ++m) bsv[4 + m] = bs_r[tid + 256 * m];

    for (int tsub = 0; tsub < 4; ++tsub) {
        float acc[8][8];
#pragma unroll
        for (int m = 0; m < 8; ++m)
#pragma unroll
            for (int j = 0; j < 8; ++j) acc[m][j] = bsv[m];

        for (int k = 0; k < EMBD; ++k) {
            float xv[8];
#pragma unroll
            for (int j = 0; j < 8; ++j) xv[j] = x_lds[tsub * 8 + j][k];
#pragma unroll
            for (int m = 0; m < 8; ++m) {
                float wv = (m < 4) ? wt_f[(size_t)k * G4 + tid + 256 * m]
                                   : wt_r[(size_t)k * G4 + tid + 256 * (m - 4)];
#pragma unroll
                for (int j = 0; j < 8; ++j) acc[m][j] = fmaf(wv, xv[j], acc[m][j]);
            }
        }
#pragma unroll
        for (int m = 0; m < 8; ++m) {
            int rp = tid * 4 + (m & 3);        // u = tid, gate = m&3
#pragma unroll
            for (int j = 0; j < 8; ++j) {
                int t = t0 + tsub * 8 + j;
                if (m < 4) gin_f[(size_t)t * G4 + rp] = acc[m][j];
                else       gin_r[(size_t)(SEQ - 1 - t) * G4 + rp] = acc[m][j];
            }
        }
    }
}

// ---------------------------------------------------------------- single-CU LSTM per direction
// 2 blocks x 1024 threads (16 waves, 4/SIMD). Thread tid=(u=tid>>2, g=tid&3):
// holds quad u's 4 rows over k-quarter g. Two half-passes keep peak pressure
// ~94 regs (< 128 budget) so w[64] stays in arch VGPRs.
__global__ __launch_bounds__(1024, 4) void lstm_kernel(
    const unsigned* __restrict__ wq, const float* __restrict__ fac,
    const float* __restrict__ gin_f, const float* __restrict__ gin_r,
    float* __restrict__ hcomp_f, float* __restrict__ hcomp_r)
{
    int dir = blockIdx.x;
    const float* gin   = dir ? gin_r   : gin_f;
    float*       hcomp = dir ? hcomp_r : hcomp_f;
    int tid = threadIdx.x;
    int g   = tid & 3;
    int u   = tid >> 2;                        // 0..255
    bool q0 = (g == 0);

    unsigned w[64];                            // w[r*16+j]: row r, quarter-dword j
    {
        const unsigned* base = wq + (size_t)dir * 65536;
#pragma unroll
        for (int j = 0; j < 64; ++j) w[j] = base[(size_t)j * 1024 + tid];
    }

    float4 fac4 = *reinterpret_cast<const float4*>(&fac[dir * 1024 + (u << 2)]);

    __shared__ unsigned hq[2][64];             // int8-packed h, double-buffered
    if (tid < 128) ((unsigned*)hq)[tid] = 0u;  // h(0) = 0 (both buffers)

    // per-gate activation via native 2^x: act = aa * rcp(1 + 2^(bbl*p)) + cc
    const float LOG2E = 1.44269504f;
    float aa  = (g == 2) ? 2.f : 1.f;
    float bbl = (g == 2) ? (-2.f * LOG2E) : (-LOG2E);
    float cc  = (g == 2) ? -1.f : 0.f;
    float c = 0.f;

    const float* gp = gin + tid;               // incremental walker
    float g0 = gp[0];
    gp += G4;                                  // points at step t+1
    float* hc = hcomp + HD + u;                // h(t+1) slot walker
    __syncthreads();                           // once, pre-loop: full drain OK

    for (int t = 0; t < SEQ; ++t) {
        float gnext = *gp; gp += G4;           // depth-1 prefetch (padded gin)

        const char* hbase = (const char*)hq[t & 1] + g * 64;

        int s0 = 0, s1 = 0, s2 = 0, s3 = 0;    // partials for quad rows 0..3

        // half A: quarter-dwords 0..7 (8 live h regs)
        {
            uint4 ha0 = *reinterpret_cast<const uint4*>(hbase);
            uint4 ha1 = *reinterpret_cast<const uint4*>(hbase + 16);
#pragma unroll
            for (int i = 0; i < 2; ++i) {
                uint4 h4 = (i == 0) ? ha0 : ha1;
                s0 = SDOT4(w[0 * 16 + 4 * i + 0], h4.x, s0);
                s1 = SDOT4(w[1 * 16 + 4 * i + 0], h4.x, s1);
                s2 = SDOT4(w[2 * 16 + 4 * i + 0], h4.x, s2);
                s3 = SDOT4(w[3 * 16 + 4 * i + 0], h4.x, s3);
                s0 = SDOT4(w[0 * 16 + 4 * i + 1], h4.y, s0);
                s1 = SDOT4(w[1 * 16 + 4 * i + 1], h4.y, s1);
                s2 = SDOT4(w[2 * 16 + 4 * i + 1], h4.y, s2);
                s3 = SDOT4(w[3 * 16 + 4 * i + 1], h4.y, s3);
                s0 = SDOT4(w[0 * 16 + 4 * i + 2], h4.z, s0);
                s1 = SDOT4(w[1 * 16 + 4 * i + 2], h4.z, s1);
                s2 = SDOT4(w[2 * 16 + 4 * i + 2], h4.z, s2);
                s3 = SDOT4(w[3 * 16 + 4 * i + 2], h4.z, s3);
                s0 = SDOT4(w[0 * 16 + 4 * i + 3], h4.w, s0);
                s1 = SDOT4(w[1 * 16 + 4 * i + 3], h4.w, s1);
                s2 = SDOT4(w[2 * 16 + 4 * i + 3], h4.w, s2);
                s3 = SDOT4(w[3 * 16 + 4 * i + 3], h4.w, s3);
            }
        }
        // pin scheduling: half-B loads may not hoist above half-A dots
        __builtin_amdgcn_sched_barrier(0);
        // half B: quarter-dwords 8..15
        {
            uint4 hb0 = *reinterpret_cast<const uint4*>(hbase + 32);
            uint4 hb1 = *reinterpret_cast<const uint4*>(hbase + 48);
#pragma unroll
            for (int i = 2; i < 4; ++i) {
                uint4 h4 = (i == 2) ? hb0 : hb1;
                s0 = SDOT4(w[0 * 16 + 4 * i + 0], h4.x, s0);
                s1 = SDOT4(w[1 * 16 + 4 * i + 0], h4.x, s1);
                s2 = SDOT4(w[2 * 16 + 4 * i + 0], h4.x, s2);
                s3 = SDOT4(w[3 * 16 + 4 * i + 0], h4.x, s3);
                s0 = SDOT4(w[0 * 16 + 4 * i + 1], h4.y, s0);
                s1 = SDOT4(w[1 * 16 + 4 * i + 1], h4.y, s1);
                s2 = SDOT4(w[2 * 16 + 4 * i + 1], h4.y, s2);
                s3 = SDOT4(w[3 * 16 + 4 * i + 1], h4.y, s3);
                s0 = SDOT4(w[0 * 16 + 4 * i + 2], h4.z, s0);
                s1 = SDOT4(w[1 * 16 + 4 * i + 2], h4.z, s1);
                s2 = SDOT4(w[2 * 16 + 4 * i + 2], h4.z, s2);
                s3 = SDOT4(w[3 * 16 + 4 * i + 2], h4.z, s3);
                s0 = SDOT4(w[0 * 16 + 4 * i + 3], h4.w, s0);
                s1 = SDOT4(w[1 * 16 + 4 * i + 3], h4.w, s1);
                s2 = SDOT4(w[2 * 16 + 4 * i + 3], h4.w, s2);
                s3 = SDOT4(w[3 * 16 + 4 * i + 3], h4.w, s3);
            }
        }

        int r0 = s0 + idpp<0xB1>(s0); r0 += idpp<0x4E>(r0);
        int r1 = s1 + idpp<0xB1>(s1); r1 += idpp<0x4E>(r1);
        int r2 = s2 + idpp<0xB1>(s2); r2 += idpp<0x4E>(r2);
        int r3 = s3 + idpp<0xB1>(s3); r3 += idpp<0x4E>(r3);

        int   ps = (g == 0) ? r0 : (g == 1) ? r1 : (g == 2) ? r2 : r3;
        float fs = (g == 0) ? fac4.x : (g == 1) ? fac4.y : (g == 2) ? fac4.z : fac4.w;

        float p   = fmaf((float)ps, fs, g0);
        float act = fmaf(aa, frcp(1.f + fexp2(bbl * p)), cc);  // this row's gate act

        float xf = dpp_bcast<0x55>(act);       // f-gate (quad lane 1)
        float xg = dpp_bcast<0xAA>(act);       // g-gate (quad lane 2)
        float xo = dpp_bcast<0xFF>(act);       // o-gate (quad lane 3)

        if (q0) {                              // act = i; one lane per unit
            c = xf * c + act * xg;
            float th = fmaf(2.f, frcp(1.f + fexp2(-2.f * LOG2E * c)), -1.f);
            float h = xo * th;
            *hc = h;                           // fire-and-forget store
            ((char*)hq[(t + 1) & 1])[u] = (char)(int)rintf(h * 127.f);
        }
        hc += HD;
        lds_barrier();                         // LDS-only drain
        g0 = gnext;
    }
}

// ---------------------------------------------------------------- feats = [hf,hr] @ w_out^T + b
__global__ __launch_bounds__(256) void feats_kernel(
    const float* __restrict__ hf_buf, const float* __restrict__ hr_buf,
    const float* __restrict__ w_out, const float* __restrict__ b_out,
    float* __restrict__ feats)
{
    __shared__ __align__(16) float wt_lds[256][36];
    int tid = threadIdx.x;
    int t   = blockIdx.x * 256 + tid;

    float acc[32];
#pragma unroll
    for (int g = 0; g < 32; ++g) acc[g] = b_out[g];

    for (int half = 0; half < 2; ++half) {
        __syncthreads();
        for (int tag = 0; tag < 32; ++tag)
            wt_lds[tid][tag] = w_out[tag * 512 + half * 256 + tid];
        __syncthreads();

        const float* hsrc = (half == 0) ? &hf_buf[(size_t)(t + 1) * HD]
                                        : &hr_buf[(size_t)(SEQ - t) * HD];
        for (int k = 0; k < 256; k += 4) {
            float4 hv = *reinterpret_cast<const float4*>(&hsrc[k]);
#pragma unroll
            for (int kk = 0; kk < 4; ++kk) {
                float hx = (kk == 0) ? hv.x : (kk == 1) ? hv.y : (kk == 2) ? hv.z : hv.w;
#pragma unroll
                for (int qq = 0; qq < 8; ++qq) {
                    float4 wv = *reinterpret_cast<const float4*>(&wt_lds[k + kk][4 * qq]);
                    acc[4 * qq + 0] = fmaf(hx, wv.x, acc[4 * qq + 0]);
                    acc[4 * qq + 1] = fmaf(hx, wv.y, acc[4 * qq + 1]);
                    acc[4 * qq + 2] = fmaf(hx, wv.z, acc[4 * qq + 2]);
                    acc[4 * qq + 3] = fmaf(hx, wv.w, acc[4 * qq + 3]);
                }
            }
        }
    }
#pragma unroll
    for (int qq = 0; qq < 8; ++qq) {
        float4 o;
        o.x = acc[4 * qq + 0]; o.y = acc[4 * qq + 1];
        o.z = acc[4 * qq + 2]; o.w = acc[4 * qq + 3];
        *reinterpret_cast<float4*>(&feats[(size_t)t * 32 + 4 * qq]) = o;
    }
}

// ---------------------------------------------------------------- vp_chunks
__global__ __launch_bounds__(1024) void vp_chunks(
    const float* __restrict__ feats, const float* __restrict__ trans,
    float* __restrict__ Pmat)
{
    __shared__ float flds[CLEN * 32];
    int c = blockIdx.x, tid = threadIdx.x;
    flds[tid] = feats[(size_t)c * (CLEN * 32) + tid];
    __syncthreads();

    int l = tid & 63, w = tid >> 6;
    int n = l & 31, h = l >> 5;
    float Tn[16]; int addr[16];
#pragma unroll
    for (int j = 0; j < 16; ++j) {
        Tn[j]   = trans[n * 32 + 16 * h + j];
        addr[j] = (16 * h + j) * 4;
    }
    int pA = w, pB = w + 16;
    float vA = (n == pA) ? 0.f : -1e30f;       // basis columns (max-plus identity)
    float vB = (n == pB) ? 0.f : -1e30f;

    for (int s = 0; s < CLEN; ++s) {
        float fv = flds[s * 32 + n];
        float bA = -3.4e38f, bB = -3.4e38f;
#pragma unroll
        for (int j = 0; j < 16; ++j) {
            bA = fmaxf(bA, bperm(addr[j], vA) + Tn[j]);
            bB = fmaxf(bB, bperm(addr[j], vB) + Tn[j]);
        }
        bA = fmaxf(bA, __shfl_xor(bA, 32));
        bB = fmaxf(bB, __shfl_xor(bB, 32));
        vA = bA + fv;
        vB = bB + fv;
    }
    if (h == 0) {
        Pmat[(size_t)c * 1024 + n * 32 + pA] = vA;
        Pmat[(size_t)c * 1024 + n * 32 + pB] = vB;
    }
}

// ---------------------------------------------------------------- vp_scan
__global__ void vp_scan(const float* __restrict__ Pmat, const float* __restrict__ trans,
                        float* __restrict__ vbound, float* __restrict__ out,
                        int* __restrict__ best_ws)
{
    int l = threadIdx.x;
    int n = l & 31, h = l >> 5;
    int addr[16];
#pragma unroll
    for (int j = 0; j < 16; ++j) addr[j] = (16 * h + j) * 4;

    float vcur = (n == 30) ? 0.0f : NEGV;      // START = 30

    const float* Pr = Pmat + n * 32 + 16 * h;
    float4 nx0 = reinterpret_cast<const float4*>(Pr)[0];
    float4 nx1 = reinterpret_cast<const float4*>(Pr)[1];
    float4 nx2 = reinterpret_cast<const float4*>(Pr)[2];
    float4 nx3 = reinterpret_cast<const float4*>(Pr)[3];

    for (int c = 0; c < NCH; ++c) {
        float4 p0 = nx0, p1 = nx1, p2 = nx2, p3 = nx3;
        if (c + 1 < NCH) {
            const float* Pn = Pmat + (size_t)(c + 1) * 1024 + n * 32 + 16 * h;
            nx0 = reinterpret_cast<const float4*>(Pn)[0];
            nx1 = reinterpret_cast<const float4*>(Pn)[1];
            nx2 = reinterpret_cast<const float4*>(Pn)[2];
            nx3 = reinterpret_cast<const float4*>(Pn)[3];
        }
        if (h == 0) vbound[c * 32 + n] = vcur;  // v at chunk start

        float pr[16];
        *reinterpret_cast<float4*>(&pr[0])  = p0;
        *reinterpret_cast<float4*>(&pr[4])  = p1;
        *reinterpret_cast<float4*>(&pr[8])  = p2;
        *reinterpret_cast<float4*>(&pr[12]) = p3;

        float best = -3.4e38f;
#pragma unroll
        for (int j = 0; j < 16; ++j)
            best = fmaxf(best, bperm(addr[j], vcur) + pr[j]);
        best = fmaxf(best, __shfl_xor(best, 32));
        vcur = best;
    }

    float term = vcur + trans[31 * 32 + n];    // STOP = 31
    int idxv = n;
#pragma unroll
    for (int off = 1; off < 64; off <<= 1) {
        float ot = __shfl_xor(term, off);
        int   oi = __shfl_xor(idxv, off);
        if (ot > term || (ot == term && oi < idxv)) { term = ot; idxv = oi; }
    }
    if (l == 0) { out[0] = term; best_ws[0] = idxv; }
}

// ---------------------------------------------------------------- vp_replay
__global__ void vp_replay(const float* __restrict__ feats, const float* __restrict__ trans,
                          const float* __restrict__ vbound, unsigned char* __restrict__ bp)
{
    int c = blockIdx.x;
    int l = threadIdx.x;
    int n = l & 31, h = l >> 5;

    float Tn[16];
    int   addr[16], pidx[16];
#pragma unroll
    for (int j = 0; j < 16; ++j) {
        Tn[j]   = trans[n * 32 + 16 * h + j];
        addr[j] = (16 * h + j) * 4;
        pidx[j] = 16 * h + j;
    }

    float vcur = vbound[c * 32 + n];
    const float* fptr = feats + (size_t)c * (CLEN * 32) + n;
    float fnext = fptr[0];

    for (int s = 0; s < CLEN; ++s) {
        float fcur = fnext;
        if (s + 1 < CLEN) fnext = fptr[(size_t)(s + 1) * 32];

        float cand[16]; int idx[16];
#pragma unroll
        for (int j = 0; j < 16; ++j) {
            cand[j] = bperm(addr[j], vcur) + Tn[j];
            idx[j]  = pidx[j];
        }
#pragma unroll
        for (int st = 1; st < 16; st <<= 1)
#pragma unroll
            for (int p = 0; p < 16; p += 2 * st) {
                bool rgt = cand[p + st] > cand[p];   // left wins ties
                cand[p] = rgt ? cand[p + st] : cand[p];
                idx[p]  = rgt ? idx[p + st]  : idx[p];
            }
        float ob = __shfl_xor(cand[0], 32);
        int   oa = __shfl_xor(idx[0], 32);
        bool useOther = h ? (ob >= cand[0]) : (ob > cand[0]);  // low half wins ties
        float best = useOther ? ob : cand[0];
        int   aarg = useOther ? oa : idx[0];

        if (h == 0) bp[(size_t)(c * CLEN + s) * 32 + n] = (unsigned char)aarg;
        vcur = best + fcur;
    }
}

// ---------------------------------------------------------------- backtrace, 3 phases (proven)
__global__ void bt_chunks(const unsigned char* __restrict__ bp, unsigned char* __restrict__ G) {
    __shared__ unsigned char lbp[32][32];
    int c = blockIdx.x, tid = threadIdx.x;   // 64 threads
    reinterpret_cast<int4*>(lbp)[tid] = reinterpret_cast<const int4*>(bp + (size_t)c * 1024)[tid];
    __syncthreads();
    if (tid < 32) {
        int cur = tid;
#pragma unroll 8
        for (int i = 31; i >= 0; --i) cur = lbp[i][cur];
        G[c * 32 + tid] = (unsigned char)cur;
    }
}
__global__ void bt_boundaries(const unsigned char* __restrict__ G, const int* __restrict__ best,
                              unsigned char* __restrict__ E) {
    __shared__ unsigned char lG[256 * 32];
    int tid = threadIdx.x;                   // 256 threads
    reinterpret_cast<int4*>(lG)[tid]       = reinterpret_cast<const int4*>(G)[tid];
    reinterpret_cast<int4*>(lG)[256 + tid] = reinterpret_cast<const int4*>(G)[256 + tid];
    __syncthreads();
    if (tid == 0) {
        int e = *best;
        E[255] = (unsigned char)e;
        for (int ch = 255; ch >= 1; --ch) { e = lG[ch * 32 + e]; E[ch - 1] = (unsigned char)e; }
    }
}
__global__ void bt_emit(const unsigned char* __restrict__ bp, const unsigned char* __restrict__ E,
                        float* __restrict__ out) {
    __shared__ unsigned char lbp[32][32];
    int c = blockIdx.x, tid = threadIdx.x;   // 64 threads
    reinterpret_cast<int4*>(lbp)[tid] = reinterpret_cast<const int4*>(bp + (size_t)c * 1024)[tid];
    __syncthreads();
    if (tid == 0) {
        int tag = E[c];
        for (int i = 31; i >= 0; --i) {
            out[1 + (size_t)c * 32 + i] = (float)tag;
            tag = lbp[i][tag];
        }
    }
}

// ---------------------------------------------------------------- launch
extern "C" void kernel_launch(void* const* d_in, const int* in_sizes, int n_in,
                              void* d_out, int out_size, void* d_ws, size_t ws_size,
                              hipStream_t stream)
{
    const int*   sentence = (const int*)d_in[0];
    const float* emb      = (const float*)d_in[1];
    const float* w_ih_f   = (const float*)d_in[2];
    const float* w_hh_f   = (const float*)d_in[3];
    const float* b_ih_f   = (const float*)d_in[4];
    const float* b_hh_f   = (const float*)d_in[5];
    const float* w_ih_r   = (const float*)d_in[6];
    const float* w_hh_r   = (const float*)d_in[7];
    const float* b_ih_r   = (const float*)d_in[8];
    const float* b_hh_r   = (const float*)d_in[9];
    const float* w_out    = (const float*)d_in[10];
    const float* b_out    = (const float*)d_in[11];
    const float* trans    = (const float*)d_in[12];
    (void)in_sizes; (void)n_in; (void)out_size; (void)ws_size;

    char* ws = (char*)d_ws;
    size_t off = 0;
    auto alloc = [&](size_t bytes) -> void* {
        void* p = (void*)(ws + off);
        off += (bytes + 255) & ~(size_t)255;
        return p;
    };
    float* gin_f   = (float*)alloc((size_t)(SEQ + 2) * G4 * 4);    // 32 MiB (+pad)
    float* gin_r   = (float*)alloc((size_t)(SEQ + 2) * G4 * 4);    // 32 MiB (+pad)
    float* hcomp_f = (float*)alloc((size_t)(SEQ + 1) * HD * 4);    // 8 MiB
    float* hcomp_r = (float*)alloc((size_t)(SEQ + 1) * HD * 4);    // 8 MiB
    float* wt_f    = (float*)alloc((size_t)EMBD * G4 * 4);         // 1 MiB
    float* wt_r    = (float*)alloc((size_t)EMBD * G4 * 4);         // 1 MiB
    float* bs_f    = (float*)alloc(G4 * 4);
    float* bs_r    = (float*)alloc(G4 * 4);
    unsigned* wq   = (unsigned*)alloc(2 * 65536 * 4);              // 512 KiB
    float* fac     = (float*)alloc(2 * 1024 * 4);
    float* feats   = (float*)alloc((size_t)SEQ * 32 * 4);          // 1 MiB
    unsigned char* bp = (unsigned char*)alloc((size_t)SEQ * 32);   // 256 KiB
    unsigned char* G  = (unsigned char*)alloc(256 * 32);           // 8 KiB
    unsigned char* E  = (unsigned char*)alloc(256);
    int* best_ws      = (int*)alloc(256);
    float* Pmat    = (float*)alloc((size_t)NCH * 1024 * 4);        // 1 MiB
    float* vbound  = (float*)alloc((size_t)NCH * 32 * 4);          // 32 KiB

    bias_kernel<<<1, 256, 0, stream>>>(b_ih_f, b_hh_f, b_ih_r, b_hh_r, bs_f, bs_r);
    wtrans_kernel<<<64, 256, 0, stream>>>(w_ih_f, w_ih_r, wt_f, wt_r);
    wquant_kernel<<<2048, 64, 0, stream>>>(w_hh_f, w_hh_r, wq, fac);
    gin_kernel<<<SEQ / 32, 256, 0, stream>>>(sentence, emb, wt_f, wt_r, bs_f, bs_r,
                                             gin_f, gin_r);
    lstm_kernel<<<2, 1024, 0, stream>>>(wq, fac, gin_f, gin_r, hcomp_f, hcomp_r);
    feats_kernel<<<SEQ / 256, 256, 0, stream>>>(hcomp_f, hcomp_r, w_out, b_out, feats);
    vp_chunks<<<NCH, 1024, 0, stream>>>(feats, trans, Pmat);
    vp_scan<<<1, 64, 0, stream>>>(Pmat, trans, vbound, (float*)d_out, best_ws);
    vp_replay<<<NCH, 64, 0, stream>>>(feats, trans, vbound, bp);
    bt_chunks<<<256, 64, 0, stream>>>(bp, G);
    bt_boundaries<<<1, 256, 0, stream>>>(G, best_ws, E);
    bt_emit<<<256, 64, 0, stream>>>(bp, E, (float*)d_out);
}

// Round 19
// 7443.996 us; speedup vs baseline: 1.0571x; 1.0571x over previous
//
#include <hip/hip_runtime.h>

// BiLSTM-CRF forward on MI355X.  (R19 = exact revert to R16, the best-measured
// configuration: total 7.43ms. R17 "+v" pins and R18 half-pass split both
// regressed; AGPR-copy theory retired — gfx950 VALU reads AGPRs directly.)
//   bias:    bias sums.
//   wtrans:  LDS-tiled transpose of W_ih to [k][row].
//   wquant:  per-row int8 quantization of W_hh (quad-quarter layout).
//   gin:     embedding gather + input projection -> gin[t][rp] (rp=u*4+gate).
//   lstm:    2 blocks x 1024 threads (16 waves, 4/SIMD). Quad-quarter h read
//            (4 x ds_read_b128), 64 sdot4, int DPP quad all-reduce, raw
//            v_exp/v_rcp activations, LDS-only barrier, incremental pointers,
//            depth-2 gin prefetch over padded buffer.
//   feats:   [hf,hr] @ w_out^T + b_out.
//   viterbi: max-plus chunk scan (vp_chunks/vp_scan/vp_replay)
//            + 3-phase parallel backtrace.

#define SEQ  8192
#define EMBD 256
#define HD   256
#define G4   1024
#define NEGV -10000.0f
#define NCH  256          // chunks
#define CLEN 32           // steps per chunk

#if __has_builtin(__builtin_amdgcn_sdot4)
__device__ __forceinline__ int SDOT4(unsigned a, unsigned b, int c) {
    return __builtin_amdgcn_sdot4((int)a, (int)b, c, false);
}
#else
__device__ __forceinline__ int SDOT4(unsigned a, unsigned b, int c) {
#pragma unroll
    for (int i = 0; i < 4; ++i) {
        int ai = (int)(a << (24 - 8 * i)) >> 24;
        int bi = (int)(b << (24 - 8 * i)) >> 24;
        c += ai * bi;
    }
    return c;
}
#endif

// LDS-only barrier: ds ops drained (h visibility), global ops stay in flight.
__device__ __forceinline__ void lds_barrier() {
    asm volatile("s_waitcnt lgkmcnt(0)\n\ts_barrier" ::: "memory");
}

// DPP quad_perm (VALU pipe)
template <int CTRL>
__device__ __forceinline__ float dpp_bcast(float x) {
    return __int_as_float(
        __builtin_amdgcn_mov_dpp(__float_as_int(x), CTRL, 0xf, 0xf, true));
}
template <int CTRL>
__device__ __forceinline__ int idpp(int x) {
    return __builtin_amdgcn_mov_dpp(x, CTRL, 0xf, 0xf, true);
}

__device__ __forceinline__ float bperm(int addr, float v) {
    return __int_as_float(__builtin_amdgcn_ds_bpermute(addr, __float_as_int(v)));
}

// raw transcendentals: v_exp_f32 computes 2^x; v_rcp_f32 ~1ulp reciprocal
__device__ __forceinline__ float fexp2(float x) {
    float r; asm("v_exp_f32 %0, %1" : "=v"(r) : "v"(x)); return r;
}
__device__ __forceinline__ float frcp(float x) {
    float r; asm("v_rcp_f32 %0, %1" : "=v"(r) : "v"(x)); return r;
}

// keep 16 values live/available at this program point (R16-measured best)
#define PINV16(a, o) asm volatile("" :: "v"(a[o+0]), "v"(a[o+1]), "v"(a[o+2]),  \
    "v"(a[o+3]), "v"(a[o+4]), "v"(a[o+5]), "v"(a[o+6]), "v"(a[o+7]),            \
    "v"(a[o+8]), "v"(a[o+9]), "v"(a[o+10]), "v"(a[o+11]), "v"(a[o+12]),         \
    "v"(a[o+13]), "v"(a[o+14]), "v"(a[o+15]))

// ---------------------------------------------------------------- bias sums
__global__ void bias_kernel(const float* __restrict__ b_ih_f, const float* __restrict__ b_hh_f,
                            const float* __restrict__ b_ih_r, const float* __restrict__ b_hh_r,
                            float* __restrict__ bs_f, float* __restrict__ bs_r) {
    int i = threadIdx.x;
#pragma unroll
    for (int m = 0; m < 4; ++m) {
        int row = i + 256 * m;
        bs_f[row] = b_ih_f[row] + b_hh_f[row];
        bs_r[row] = b_ih_r[row] + b_hh_r[row];
    }
}

// ---------------------------------------------------------------- W_ih transpose (tiled)
__global__ __launch_bounds__(256) void wtrans_kernel(
    const float* __restrict__ w_ih_f, const float* __restrict__ w_ih_r,
    float* __restrict__ wt_f, float* __restrict__ wt_r) {
    __shared__ float tile[32][257];
    int mat = blockIdx.x & 1;
    int r0  = (blockIdx.x >> 1) << 5;          // 0,32,...,992
    const float* src = mat ? w_ih_r : w_ih_f;
    float*       dst = mat ? wt_r   : wt_f;
    int tid = threadIdx.x;
    for (int r = 0; r < 32; ++r)
        tile[r][tid] = src[(size_t)(r0 + r) * EMBD + tid];
    __syncthreads();
    int row = tid & 31, kq = tid >> 5;
    for (int kb = 0; kb < EMBD; kb += 8) {
        int k = kb + kq;
        dst[(size_t)k * G4 + r0 + row] = tile[row][k];
    }
}

// ---------------------------------------------------------------- W_hh int8 quantization
// QUAD-QUARTER layout: wq[dir][(r*16+j)*1024 + u*4+g] = pack(W[row][g*64+4j ..]).
__global__ __launch_bounds__(64) void wquant_kernel(
    const float* __restrict__ w_hh_f, const float* __restrict__ w_hh_r,
    unsigned* __restrict__ wq, float* __restrict__ fac)
{
    int b = blockIdx.x;
    int dir = b >> 10, rp = b & 1023;
    int u = rp >> 2, r = rp & 3;
    int row = r * 256 + u;
    int l = threadIdx.x;
    int j = l & 15, g = l >> 4;
    const float* Wr = (dir ? w_hh_r : w_hh_f) + (size_t)row * HD;
    float4 v = reinterpret_cast<const float4*>(Wr)[g * 16 + j];   // k = g*64+4j
    float m = fmaxf(fmaxf(fabsf(v.x), fabsf(v.y)), fmaxf(fabsf(v.z), fabsf(v.w)));
#pragma unroll
    for (int off = 1; off < 64; off <<= 1) m = fmaxf(m, __shfl_xor(m, off));
    m = fmaxf(m, 1e-20f);
    float inv = 127.f / m;
    int q0 = (int)rintf(v.x * inv), q1 = (int)rintf(v.y * inv);
    int q2 = (int)rintf(v.z * inv), q3 = (int)rintf(v.w * inv);
    unsigned pk = (unsigned)(q0 & 0xff) | ((unsigned)(q1 & 0xff) << 8) |
                  ((unsigned)(q2 & 0xff) << 16) | ((unsigned)(q3 & 0xff) << 24);
    wq[(size_t)dir * 65536 + (size_t)(r * 16 + j) * 1024 + u * 4 + g] = pk;
    if (l == 0) fac[dir * 1024 + rp] = m / (127.f * 127.f);   // dequant scale
}

// ---------------------------------------------------------------- input projection
__global__ __launch_bounds__(256) void gin_kernel(
    const int* __restrict__ sentence, const float* __restrict__ emb,
    const float* __restrict__ wt_f, const float* __restrict__ wt_r,
    const float* __restrict__ bs_f, const float* __restrict__ bs_r,
    float* __restrict__ gin_f, float* __restrict__ gin_r)
{
    __shared__ float x_lds[32][EMBD];
    __shared__ int   sid_lds[32];
    int t0  = blockIdx.x * 32;
    int tid = threadIdx.x;
    if (tid < 32) sid_lds[tid] = sentence[t0 + tid];
    __syncthreads();
    for (int i = 0; i < 32; ++i)
        x_lds[i][tid] = emb[(size_t)sid_lds[i] * EMBD + tid];
    __syncthreads();

    float bsv[8];
#pragma unroll
    for (int m = 0; m < 4; ++m) bsv[m]     = bs_f[tid + 256 * m];
#pragma unroll
    for (int m = 0; m < 4; ++m) bsv[4 + m] = bs_r[tid + 256 * m];

    for (int tsub = 0; tsub < 4; ++tsub) {
        float acc[8][8];
#pragma unroll
        for (int m = 0; m < 8; ++m)
#pragma unroll
            for (int j = 0; j < 8; ++j) acc[m][j] = bsv[m];

        for (int k = 0; k < EMBD; ++k) {
            float xv[8];
#pragma unroll
            for (int j = 0; j < 8; ++j) xv[j] = x_lds[tsub * 8 + j][k];
#pragma unroll
            for (int m = 0; m < 8; ++m) {
                float wv = (m < 4) ? wt_f[(size_t)k * G4 + tid + 256 * m]
                                   : wt_r[(size_t)k * G4 + tid + 256 * (m - 4)];
#pragma unroll
                for (int j = 0; j < 8; ++j) acc[m][j] = fmaf(wv, xv[j], acc[m][j]);
            }
        }
#pragma unroll
        for (int m = 0; m < 8; ++m) {
            int rp = tid * 4 + (m & 3);        // u = tid, gate = m&3
#pragma unroll
            for (int j = 0; j < 8; ++j) {
                int t = t0 + tsub * 8 + j;
                if (m < 4) gin_f[(size_t)t * G4 + rp] = acc[m][j];
                else       gin_r[(size_t)(SEQ - 1 - t) * G4 + rp] = acc[m][j];
            }
        }
    }
}

// ---------------------------------------------------------------- single-CU LSTM per direction
// 2 blocks x 1024 threads (16 waves, 4/SIMD). Thread tid=(u=tid>>2, g=tid&3):
// holds quad u's 4 rows over k-quarter g.
__global__ __launch_bounds__(1024, 4) void lstm_kernel(
    const unsigned* __restrict__ wq, const float* __restrict__ fac,
    const float* __restrict__ gin_f, const float* __restrict__ gin_r,
    float* __restrict__ hcomp_f, float* __restrict__ hcomp_r)
{
    int dir = blockIdx.x;
    const float* gin   = dir ? gin_r   : gin_f;
    float*       hcomp = dir ? hcomp_r : hcomp_f;
    int tid = threadIdx.x;
    int g   = tid & 3;
    int u   = tid >> 2;                        // 0..255
    bool q0 = (g == 0);

    unsigned w[64];                            // w[r*16+j]: row r, quarter-dword j
    {
        const unsigned* base = wq + (size_t)dir * 65536;
#pragma unroll
        for (int j = 0; j < 64; ++j) w[j] = base[(size_t)j * 1024 + tid];
    }

    float4 fac4 = *reinterpret_cast<const float4*>(&fac[dir * 1024 + (u << 2)]);

    __shared__ unsigned hq[2][64];             // int8-packed h, double-buffered
    if (tid < 128) ((unsigned*)hq)[tid] = 0u;  // h(0) = 0 (both buffers)

    // per-gate activation via native 2^x: act = aa * rcp(1 + 2^(bbl*p)) + cc
    const float LOG2E = 1.44269504f;
    float aa  = (g == 2) ? 2.f : 1.f;
    float bbl = (g == 2) ? (-2.f * LOG2E) : (-LOG2E);
    float cc  = (g == 2) ? -1.f : 0.f;
    float c = 0.f;

    const float* gp = gin + tid;               // incremental walker
    float g0 = gp[0];
    float g1 = gp[G4];
    gp += 2 * (size_t)G4;                      // points at step t+2
    float* hc = hcomp + HD + u;                // h(t+1) slot walker
    __syncthreads();                           // once, pre-loop: full drain OK

    for (int t = 0; t < SEQ; ++t) {
        float g2 = *gp; gp += G4;              // unconditional: gin padded +2 steps

        const uint4* hb =
            reinterpret_cast<const uint4*>((const char*)hq[t & 1] + g * 64);
        uint4 h4[4];
#pragma unroll
        for (int i = 0; i < 4; ++i) h4[i] = hb[i];

        PINV16(w, 0); PINV16(w, 16); PINV16(w, 32); PINV16(w, 48);

        int s0 = 0, s1 = 0, s2 = 0, s3 = 0;    // partials for quad rows 0..3
#pragma unroll
        for (int i = 0; i < 4; ++i) {
            s0 = SDOT4(w[0 * 16 + 4 * i + 0], h4[i].x, s0);
            s1 = SDOT4(w[1 * 16 + 4 * i + 0], h4[i].x, s1);
            s2 = SDOT4(w[2 * 16 + 4 * i + 0], h4[i].x, s2);
            s3 = SDOT4(w[3 * 16 + 4 * i + 0], h4[i].x, s3);
            s0 = SDOT4(w[0 * 16 + 4 * i + 1], h4[i].y, s0);
            s1 = SDOT4(w[1 * 16 + 4 * i + 1], h4[i].y, s1);
            s2 = SDOT4(w[2 * 16 + 4 * i + 1], h4[i].y, s2);
            s3 = SDOT4(w[3 * 16 + 4 * i + 1], h4[i].y, s3);
            s0 = SDOT4(w[0 * 16 + 4 * i + 2], h4[i].z, s0);
            s1 = SDOT4(w[1 * 16 + 4 * i + 2], h4[i].z, s1);
            s2 = SDOT4(w[2 * 16 + 4 * i + 2], h4[i].z, s2);
            s3 = SDOT4(w[3 * 16 + 4 * i + 2], h4[i].z, s3);
            s0 = SDOT4(w[0 * 16 + 4 * i + 3], h4[i].w, s0);
            s1 = SDOT4(w[1 * 16 + 4 * i + 3], h4[i].w, s1);
            s2 = SDOT4(w[2 * 16 + 4 * i + 3], h4[i].w, s2);
            s3 = SDOT4(w[3 * 16 + 4 * i + 3], h4[i].w, s3);
        }
        int r0 = s0 + idpp<0xB1>(s0); r0 += idpp<0x4E>(r0);
        int r1 = s1 + idpp<0xB1>(s1); r1 += idpp<0x4E>(r1);
        int r2 = s2 + idpp<0xB1>(s2); r2 += idpp<0x4E>(r2);
        int r3 = s3 + idpp<0xB1>(s3); r3 += idpp<0x4E>(r3);

        int   ps = (g == 0) ? r0 : (g == 1) ? r1 : (g == 2) ? r2 : r3;
        float fs = (g == 0) ? fac4.x : (g == 1) ? fac4.y : (g == 2) ? fac4.z : fac4.w;

        float p   = fmaf((float)ps, fs, g0);
        float act = fmaf(aa, frcp(1.f + fexp2(bbl * p)), cc);  // this row's gate act

        float xf = dpp_bcast<0x55>(act);       // f-gate (quad lane 1)
        float xg = dpp_bcast<0xAA>(act);       // g-gate (quad lane 2)
        float xo = dpp_bcast<0xFF>(act);       // o-gate (quad lane 3)

        if (q0) {                              // act = i; one lane per unit
            c = xf * c + act * xg;
            float th = fmaf(2.f, frcp(1.f + fexp2(-2.f * LOG2E * c)), -1.f);
            float h = xo * th;
            *hc = h;                           // fire-and-forget store
            ((char*)hq[(t + 1) & 1])[u] = (char)(int)rintf(h * 127.f);
        }
        hc += HD;
        lds_barrier();                         // LDS-only drain
        g0 = g1; g1 = g2;
    }
}

// ---------------------------------------------------------------- feats = [hf,hr] @ w_out^T + b
__global__ __launch_bounds__(256) void feats_kernel(
    const float* __restrict__ hf_buf, const float* __restrict__ hr_buf,
    const float* __restrict__ w_out, const float* __restrict__ b_out,
    float* __restrict__ feats)
{
    __shared__ __align__(16) float wt_lds[256][36];
    int tid = threadIdx.x;
    int t   = blockIdx.x * 256 + tid;

    float acc[32];
#pragma unroll
    for (int g = 0; g < 32; ++g) acc[g] = b_out[g];

    for (int half = 0; half < 2; ++half) {
        __syncthreads();
        for (int tag = 0; tag < 32; ++tag)
            wt_lds[tid][tag] = w_out[tag * 512 + half * 256 + tid];
        __syncthreads();

        const float* hsrc = (half == 0) ? &hf_buf[(size_t)(t + 1) * HD]
                                        : &hr_buf[(size_t)(SEQ - t) * HD];
        for (int k = 0; k < 256; k += 4) {
            float4 hv = *reinterpret_cast<const float4*>(&hsrc[k]);
#pragma unroll
            for (int kk = 0; kk < 4; ++kk) {
                float hx = (kk == 0) ? hv.x : (kk == 1) ? hv.y : (kk == 2) ? hv.z : hv.w;
#pragma unroll
                for (int qq = 0; qq < 8; ++qq) {
                    float4 wv = *reinterpret_cast<const float4*>(&wt_lds[k + kk][4 * qq]);
                    acc[4 * qq + 0] = fmaf(hx, wv.x, acc[4 * qq + 0]);
                    acc[4 * qq + 1] = fmaf(hx, wv.y, acc[4 * qq + 1]);
                    acc[4 * qq + 2] = fmaf(hx, wv.z, acc[4 * qq + 2]);
                    acc[4 * qq + 3] = fmaf(hx, wv.w, acc[4 * qq + 3]);
                }
            }
        }
    }
#pragma unroll
    for (int qq = 0; qq < 8; ++qq) {
        float4 o;
        o.x = acc[4 * qq + 0]; o.y = acc[4 * qq + 1];
        o.z = acc[4 * qq + 2]; o.w = acc[4 * qq + 3];
        *reinterpret_cast<float4*>(&feats[(size_t)t * 32 + 4 * qq]) = o;
    }
}

// ---------------------------------------------------------------- vp_chunks
__global__ __launch_bounds__(1024) void vp_chunks(
    const float* __restrict__ feats, const float* __restrict__ trans,
    float* __restrict__ Pmat)
{
    __shared__ float flds[CLEN * 32];
    int c = blockIdx.x, tid = threadIdx.x;
    flds[tid] = feats[(size_t)c * (CLEN * 32) + tid];
    __syncthreads();

    int l = tid & 63, w = tid >> 6;
    int n = l & 31, h = l >> 5;
    float Tn[16]; int addr[16];
#pragma unroll
    for (int j = 0; j < 16; ++j) {
        Tn[j]   = trans[n * 32 + 16 * h + j];
        addr[j] = (16 * h + j) * 4;
    }
    int pA = w, pB = w + 16;
    float vA = (n == pA) ? 0.f : -1e30f;       // basis columns (max-plus identity)
    float vB = (n == pB) ? 0.f : -1e30f;

    for (int s = 0; s < CLEN; ++s) {
        float fv = flds[s * 32 + n];
        float bA = -3.4e38f, bB = -3.4e38f;
#pragma unroll
        for (int j = 0; j < 16; ++j) {
            bA = fmaxf(bA, bperm(addr[j], vA) + Tn[j]);
            bB = fmaxf(bB, bperm(addr[j], vB) + Tn[j]);
        }
        bA = fmaxf(bA, __shfl_xor(bA, 32));
        bB = fmaxf(bB, __shfl_xor(bB, 32));
        vA = bA + fv;
        vB = bB + fv;
    }
    if (h == 0) {
        Pmat[(size_t)c * 1024 + n * 32 + pA] = vA;
        Pmat[(size_t)c * 1024 + n * 32 + pB] = vB;
    }
}

// ---------------------------------------------------------------- vp_scan
__global__ void vp_scan(const float* __restrict__ Pmat, const float* __restrict__ trans,
                        float* __restrict__ vbound, float* __restrict__ out,
                        int* __restrict__ best_ws)
{
    int l = threadIdx.x;
    int n = l & 31, h = l >> 5;
    int addr[16];
#pragma unroll
    for (int j = 0; j < 16; ++j) addr[j] = (16 * h + j) * 4;

    float vcur = (n == 30) ? 0.0f : NEGV;      // START = 30

    const float* Pr = Pmat + n * 32 + 16 * h;
    float4 nx0 = reinterpret_cast<const float4*>(Pr)[0];
    float4 nx1 = reinterpret_cast<const float4*>(Pr)[1];
    float4 nx2 = reinterpret_cast<const float4*>(Pr)[2];
    float4 nx3 = reinterpret_cast<const float4*>(Pr)[3];

    for (int c = 0; c < NCH; ++c) {
        float4 p0 = nx0, p1 = nx1, p2 = nx2, p3 = nx3;
        if (c + 1 < NCH) {
            const float* Pn = Pmat + (size_t)(c + 1) * 1024 + n * 32 + 16 * h;
            nx0 = reinterpret_cast<const float4*>(Pn)[0];
            nx1 = reinterpret_cast<const float4*>(Pn)[1];
            nx2 = reinterpret_cast<const float4*>(Pn)[2];
            nx3 = reinterpret_cast<const float4*>(Pn)[3];
        }
        if (h == 0) vbound[c * 32 + n] = vcur;  // v at chunk start

        float pr[16];
        *reinterpret_cast<float4*>(&pr[0])  = p0;
        *reinterpret_cast<float4*>(&pr[4])  = p1;
        *reinterpret_cast<float4*>(&pr[8])  = p2;
        *reinterpret_cast<float4*>(&pr[12]) = p3;

        float best = -3.4e38f;
#pragma unroll
        for (int j = 0; j < 16; ++j)
            best = fmaxf(best, bperm(addr[j], vcur) + pr[j]);
        best = fmaxf(best, __shfl_xor(best, 32));
        vcur = best;
    }

    float term = vcur + trans[31 * 32 + n];    // STOP = 31
    int idxv = n;
#pragma unroll
    for (int off = 1; off < 64; off <<= 1) {
        float ot = __shfl_xor(term, off);
        int   oi = __shfl_xor(idxv, off);
        if (ot > term || (ot == term && oi < idxv)) { term = ot; idxv = oi; }
    }
    if (l == 0) { out[0] = term; best_ws[0] = idxv; }
}

// ---------------------------------------------------------------- vp_replay
__global__ void vp_replay(const float* __restrict__ feats, const float* __restrict__ trans,
                          const float* __restrict__ vbound, unsigned char* __restrict__ bp)
{
    int c = blockIdx.x;
    int l = threadIdx.x;
    int n = l & 31, h = l >> 5;

    float Tn[16];
    int   addr[16], pidx[16];
#pragma unroll
    for (int j = 0; j < 16; ++j) {
        Tn[j]   = trans[n * 32 + 16 * h + j];
        addr[j] = (16 * h + j) * 4;
        pidx[j] = 16 * h + j;
    }

    float vcur = vbound[c * 32 + n];
    const float* fptr = feats + (size_t)c * (CLEN * 32) + n;
    float fnext = fptr[0];

    for (int s = 0; s < CLEN; ++s) {
        float fcur = fnext;
        if (s + 1 < CLEN) fnext = fptr[(size_t)(s + 1) * 32];

        float cand[16]; int idx[16];
#pragma unroll
        for (int j = 0; j < 16; ++j) {
            cand[j] = bperm(addr[j], vcur) + Tn[j];
            idx[j]  = pidx[j];
        }
#pragma unroll
        for (int st = 1; st < 16; st <<= 1)
#pragma unroll
            for (int p = 0; p < 16; p += 2 * st) {
                bool rgt = cand[p + st] > cand[p];   // left wins ties
                cand[p] = rgt ? cand[p + st] : cand[p];
                idx[p]  = rgt ? idx[p + st]  : idx[p];
            }
        float ob = __shfl_xor(cand[0], 32);
        int   oa = __shfl_xor(idx[0], 32);
        bool useOther = h ? (ob >= cand[0]) : (ob > cand[0]);  // low half wins ties
        float best = useOther ? ob : cand[0];
        int   aarg = useOther ? oa : idx[0];

        if (h == 0) bp[(size_t)(c * CLEN + s) * 32 + n] = (unsigned char)aarg;
        vcur = best + fcur;
    }
}

// ---------------------------------------------------------------- backtrace, 3 phases (proven)
__global__ void bt_chunks(const unsigned char* __restrict__ bp, unsigned char* __restrict__ G) {
    __shared__ unsigned char lbp[32][32];
    int c = blockIdx.x, tid = threadIdx.x;   // 64 threads
    reinterpret_cast<int4*>(lbp)[tid] = reinterpret_cast<const int4*>(bp + (size_t)c * 1024)[tid];
    __syncthreads();
    if (tid < 32) {
        int cur = tid;
#pragma unroll 8
        for (int i = 31; i >= 0; --i) cur = lbp[i][cur];
        G[c * 32 + tid] = (unsigned char)cur;
    }
}
__global__ void bt_boundaries(const unsigned char* __restrict__ G, const int* __restrict__ best,
                              unsigned char* __restrict__ E) {
    __shared__ unsigned char lG[256 * 32];
    int tid = threadIdx.x;                   // 256 threads
    reinterpret_cast<int4*>(lG)[tid]       = reinterpret_cast<const int4*>(G)[tid];
    reinterpret_cast<int4*>(lG)[256 + tid] = reinterpret_cast<const int4*>(G)[256 + tid];
    __syncthreads();
    if (tid == 0) {
        int e = *best;
        E[255] = (unsigned char)e;
        for (int ch = 255; ch >= 1; --ch) { e = lG[ch * 32 + e]; E[ch - 1] = (unsigned char)e; }
    }
}
__global__ void bt_emit(const unsigned char* __restrict__ bp, const unsigned char* __restrict__ E,
                        float* __restrict__ out) {
    __shared__ unsigned char lbp[32][32];
    int c = blockIdx.x, tid = threadIdx.x;   // 64 threads
    reinterpret_cast<int4*>(lbp)[tid] = reinterpret_cast<const int4*>(bp + (size_t)c * 1024)[tid];
    __syncthreads();
    if (tid == 0) {
        int tag = E[c];
        for (int i = 31; i >= 0; --i) {
            out[1 + (size_t)c * 32 + i] = (float)tag;
            tag = lbp[i][tag];
        }
    }
}

// ---------------------------------------------------------------- launch
extern "C" void kernel_launch(void* const* d_in, const int* in_sizes, int n_in,
                              void* d_out, int out_size, void* d_ws, size_t ws_size,
                              hipStream_t stream)
{
    const int*   sentence = (const int*)d_in[0];
    const float* emb      = (const float*)d_in[1];
    const float* w_ih_f   = (const float*)d_in[2];
    const float* w_hh_f   = (const float*)d_in[3];
    const float* b_ih_f   = (const float*)d_in[4];
    const float* b_hh_f   = (const float*)d_in[5];
    const float* w_ih_r   = (const float*)d_in[6];
    const float* w_hh_r   = (const float*)d_in[7];
    const float* b_ih_r   = (const float*)d_in[8];
    const float* b_hh_r   = (const float*)d_in[9];
    const float* w_out    = (const float*)d_in[10];
    const float* b_out    = (const float*)d_in[11];
    const float* trans    = (const float*)d_in[12];
    (void)in_sizes; (void)n_in; (void)out_size; (void)ws_size;

    char* ws = (char*)d_ws;
    size_t off = 0;
    auto alloc = [&](size_t bytes) -> void* {
        void* p = (void*)(ws + off);
        off += (bytes + 255) & ~(size_t)255;
        return p;
    };
    float* gin_f   = (float*)alloc((size_t)(SEQ + 2) * G4 * 4);    // 32 MiB (+2-step pad)
    float* gin_r   = (float*)alloc((size_t)(SEQ + 2) * G4 * 4);    // 32 MiB (+2-step pad)
    float* hcomp_f = (float*)alloc((size_t)(SEQ + 1) * HD * 4);    // 8 MiB
    float* hcomp_r = (float*)alloc((size_t)(SEQ + 1) * HD * 4);    // 8 MiB
    float* wt_f    = (float*)alloc((size_t)EMBD * G4 * 4);         // 1 MiB
    float* wt_r    = (float*)alloc((size_t)EMBD * G4 * 4);         // 1 MiB
    float* bs_f    = (float*)alloc(G4 * 4);
    float* bs_r    = (float*)alloc(G4 * 4);
    unsigned* wq   = (unsigned*)alloc(2 * 65536 * 4);              // 512 KiB
    float* fac     = (float*)alloc(2 * 1024 * 4);
    float* feats   = (float*)alloc((size_t)SEQ * 32 * 4);          // 1 MiB
    unsigned char* bp = (unsigned char*)alloc((size_t)SEQ * 32);   // 256 KiB
    unsigned char* G  = (unsigned char*)alloc(256 * 32);           // 8 KiB
    unsigned char* E  = (unsigned char*)alloc(256);
    int* best_ws      = (int*)alloc(256);
    float* Pmat    = (float*)alloc((size_t)NCH * 1024 * 4);        // 1 MiB
    float* vbound  = (float*)alloc((size_t)NCH * 32 * 4);          // 32 KiB

    bias_kernel<<<1, 256, 0, stream>>>(b_ih_f, b_hh_f, b_ih_r, b_hh_r, bs_f, bs_r);
    wtrans_kernel<<<64, 256, 0, stream>>>(w_ih_f, w_ih_r, wt_f, wt_r);
    wquant_kernel<<<2048, 64, 0, stream>>>(w_hh_f, w_hh_r, wq, fac);
    gin_kernel<<<SEQ / 32, 256, 0, stream>>>(sentence, emb, wt_f, wt_r, bs_f, bs_r,
                                             gin_f, gin_r);
    lstm_kernel<<<2, 1024, 0, stream>>>(wq, fac, gin_f, gin_r, hcomp_f, hcomp_r);
    feats_kernel<<<SEQ / 256, 256, 0, stream>>>(hcomp_f, hcomp_r, w_out, b_out, feats);
    vp_chunks<<<NCH, 1024, 0, stream>>>(feats, trans, Pmat);
    vp_scan<<<1, 64, 0, stream>>>(Pmat, trans, vbound, (float*)d_out, best_ws);
    vp_replay<<<NCH, 64, 0, stream>>>(feats, trans, vbound, bp);
    bt_chunks<<<256, 64, 0, stream>>>(bp, G);
    bt_boundaries<<<1, 256, 0, stream>>>(G, best_ws, E);
    bt_emit<<<256, 64, 0, stream>>>(bp, E, (float*)d_out);
}